// Round 11
// baseline (2783.951 us; speedup 1.0000x reference)
//
#include <hip/hip_runtime.h>

// f32 storage; bf16 only as MFMA inputs (f32 accumulate). One fused kernel per layer.
// R8 base + MFMA-based attention (kills the scalar-attention VGPR peak).
// 256 threads / 4 waves; wave g handles bn g's attention via matrix cores.
// NOTE: no min-waves arg in __launch_bounds__ — it makes the allocator spill (R4/R6/R7).

#define B_   64
#define S_   12
#define N_   170
#define BN_  (B_*N_)      // 10880
#define E_   128
#define L_   4
#define C_   2
#define H_   8
#define DH_  16
#define FF_  512
#define EPS_ 1e-5f
#define THREADS 256

typedef unsigned short u16;
typedef __attribute__((ext_vector_type(4))) float f32x4;
typedef __attribute__((ext_vector_type(8))) u16   us8;
typedef __attribute__((ext_vector_type(4))) u16   us4;
typedef __attribute__((ext_vector_type(8))) __bf16 bf16x8;
union FragU { us8 u; bf16x8 b; };

__device__ __forceinline__ u16 f2bf(float f) {            // native RNE cvt
    __bf16 h = (__bf16)f;
    return __builtin_bit_cast(u16, h);
}
__device__ __forceinline__ float bf2f(u16 s) {
    return __builtin_bit_cast(float, (unsigned)s << 16);
}

// ---------------- weight pre-pack into MFMA B-fragment order ----------------
// Layer layout (u16): cq 2x16384 @0 | sa 4x16384 @32768 | ck 6x16384 @98304
//                     | ca 8x16384 @196608 | ff1 @327680 | ff2 @393216 ; stride 458752
__global__ void k_wpack(const float* __restrict__ cq, const float* __restrict__ sa,
                        const float* __restrict__ ck, const float* __restrict__ ca,
                        const float* __restrict__ f1, const float* __restrict__ f2,
                        u16* __restrict__ wp) {
    int f  = blockIdx.x * 256 + threadIdx.x;    // frag id, total 229376
    int l  = f / 57344, fl = f % 57344;
    const float* src; int sk, so, KS, q;
    if (fl < 4096)        { int tap = fl >> 11; q = fl & 2047; KS = 4;
                            src = cq + (size_t)l*49152 + tap;            sk = 3;   so = 384; }
    else if (fl < 12288)  { int j = (fl - 4096) >> 11; q = fl & 2047; KS = 4;
                            src = sa + (size_t)(l*4 + j)*16384;          sk = 128; so = 1;   }
    else if (fl < 24576)  { int ct = (fl - 12288) >> 11; q = fl & 2047; KS = 4;
                            int ci = ct / 3, tap = ct % 3;
                            src = ck + (size_t)(l*2 + ci)*49152 + tap;   sk = 3;   so = 384; }
    else if (fl < 40960)  { int cj = (fl - 24576) >> 11; q = fl & 2047; KS = 4;
                            src = ca + (size_t)(l*8 + cj)*16384;         sk = 128; so = 1;   }
    else if (fl < 49152)  { q = fl - 40960; KS = 4;
                            src = f1 + (size_t)l*65536;                  sk = 512; so = 1;   }
    else                  { q = fl - 49152; KS = 16;
                            src = f2 + (size_t)l*65536;                  sk = 128; so = 1;   }
    int lane = q & 63, tt = q >> 6;
    int ks = tt % KS, ntile = tt / KS;
    int k0 = ks*32 + ((lane >> 4) << 3);
    int o  = ntile*16 + (lane & 15);
    us8 w;
    #pragma unroll
    for (int i = 0; i < 8; i++) w[i] = f2bf(src[(size_t)(k0 + i)*sk + (size_t)o*so]);
    *(us8*)(wp + (size_t)f*8) = w;
}

// ---------------- device helpers ----------------
__device__ __forceinline__ void stage48(const float* __restrict__ src, u16* dst, int t) {
    for (int i = t; i < 1536; i += THREADS) {
        const f32x4 v = __builtin_nontemporal_load(((const f32x4*)src) + i);
        int elem = i << 2;
        int row = elem >> 7, colb = (elem & 127) << 1;
        us4 w; w[0] = f2bf(v[0]); w[1] = f2bf(v[1]); w[2] = f2bf(v[2]); w[3] = f2bf(v[3]);
        *(us4*)((char*)dst + (((row << 8) + colb) ^ ((row & 7) << 4))) = w;
    }
}

__device__ __forceinline__ void stage48_embed(const float* __restrict__ x,
    const float* __restrict__ ew, const float* __restrict__ eb,
    const float* __restrict__ pe, int bn0, u16* dst, int t) {
    for (int i = t; i < 1536; i += THREADS) {
        int elem = i << 2;
        int row = elem >> 7, col = elem & 127;
        int g = row / 12, s = row - g*12;
        int bn = bn0 + g, b = bn / N_, n = bn - b*N_;
        float xv = __builtin_nontemporal_load(x + (b*S_ + s)*N_ + n);
        const f32x4 w  = *(const f32x4*)(ew + col);
        const f32x4 bb = *(const f32x4*)(eb + col);
        const f32x4 p  = *(const f32x4*)(pe + s*E_ + col);
        us4 o; o[0] = f2bf(xv*w[0] + bb[0] + p[0]); o[1] = f2bf(xv*w[1] + bb[1] + p[1]);
               o[2] = f2bf(xv*w[2] + bb[2] + p[2]); o[3] = f2bf(xv*w[3] + bb[3] + p[3]);
        *(us4*)((char*)dst + (((row << 8) + (col << 1)) ^ ((row & 7) << 4))) = o;
    }
}

__device__ __forceinline__ void acc_init(f32x4 (&acc)[3][2], const float* bias, int wave, int lane) {
    #pragma unroll
    for (int nl = 0; nl < 2; nl++) {
        float bv = bias ? bias[(wave*2 + nl)*16 + (lane & 15)] : 0.f;
        #pragma unroll
        for (int mt = 0; mt < 3; mt++) {
            acc[mt][nl][0] = bv; acc[mt][nl][1] = bv; acc[mt][nl][2] = bv; acc[mt][nl][3] = bv;
        }
    }
}

// GEMM: D[48][wave's 32 cols] += A[48][128] * W ; A swizzled bf16 LDS (256B rows)
template<int KSTOT>
__device__ __forceinline__ void gemm48(const u16* A, const us8* __restrict__ WP, int ksOff,
                                       f32x4 (&acc)[3][2], int wave, int lane) {
    #pragma unroll
    for (int ks = 0; ks < 4; ks++) {
        bf16x8 a[3];
        #pragma unroll
        for (int mt = 0; mt < 3; mt++) {
            int row  = mt*16 + (lane & 15);
            int colb = (ks*32 + ((lane >> 4) << 3)) << 1;
            FragU fu; fu.u = *(const us8*)((const char*)A + (((row << 8) + colb) ^ ((row & 7) << 4)));
            a[mt] = fu.b;
        }
        #pragma unroll
        for (int nl = 0; nl < 2; nl++) {
            FragU fb; fb.u = WP[((wave*2 + nl)*KSTOT + ksOff + ks)*64 + lane];
            #pragma unroll
            for (int mt = 0; mt < 3; mt++)
                acc[mt][nl] = __builtin_amdgcn_mfma_f32_16x16x32_bf16(a[mt], fb.b, acc[mt][nl], 0, 0, 0);
        }
    }
}

// GEMM with per-mtile shifted source rows (conv taps; sr<0 -> zero row)
__device__ __forceinline__ void gemm48_rows(const u16* A, const u16* ZR, const int (&sr)[3],
                                            const us8* __restrict__ WP,
                                            f32x4 (&acc)[3][2], int wave, int lane) {
    #pragma unroll
    for (int ks = 0; ks < 4; ks++) {
        bf16x8 a[3];
        #pragma unroll
        for (int mt = 0; mt < 3; mt++) {
            int colb = (ks*32 + ((lane >> 4) << 3)) << 1;
            const char* p = (sr[mt] >= 0)
                ? (const char*)A + (((sr[mt] << 8) + colb) ^ ((sr[mt] & 7) << 4))
                : (const char*)ZR + colb;
            FragU fu; fu.u = *(const us8*)p;
            a[mt] = fu.b;
        }
        #pragma unroll
        for (int nl = 0; nl < 2; nl++) {
            FragU fb; fb.u = WP[((wave*2 + nl)*4 + ks)*64 + lane];
            #pragma unroll
            for (int mt = 0; mt < 3; mt++)
                acc[mt][nl] = __builtin_amdgcn_mfma_f32_16x16x32_bf16(a[mt], fb.b, acc[mt][nl], 0, 0, 0);
        }
    }
}

template<bool RELU>
__device__ __forceinline__ void acc_store_bf(const f32x4 (&acc)[3][2], u16* Bp, int wave, int lane) {
    #pragma unroll
    for (int mt = 0; mt < 3; mt++)
    #pragma unroll
    for (int nl = 0; nl < 2; nl++)
    #pragma unroll
    for (int r = 0; r < 4; r++) {
        int row = mt*16 + ((lane >> 4) << 2) + r;
        int col = (wave*2 + nl)*16 + (lane & 15);
        float v = acc[mt][nl][r];
        if (RELU) v = fmaxf(v, 0.f);
        *(u16*)((char*)Bp + (((row << 8) + (col << 1)) ^ ((row & 7) << 4))) = f2bf(v);
    }
}

__device__ __forceinline__ float lds_bf(const u16* Bp, int row, int col) {
    return bf2f(*(const u16*)((const char*)Bp + (((row << 8) + (col << 1)) ^ ((row & 7) << 4))));
}

// ---------------- MFMA attention: wave g handles bn g, 8 heads sequentially ----------------
// QA: Q tile (replaced in place by attention output), KB: K tile, VB: V tile.
// PS: per-wave 16x32 bf16 scratch (1 KB each), zero-padded; ZR: 256 B of zeros.
template<bool MASK>
__device__ __forceinline__ void attn_mfma(u16* QA, const u16* KB, const u16* VB,
                                          u16* PSall, const u16* ZR, int wave, int lane) {
    u16* ps = PSall + wave*512;
    { us8 z8 = {0,0,0,0,0,0,0,0}; *(us8*)(ps + lane*8) = z8; }   // zero 16x32 slice
    const int g   = wave;
    const int ko  = (lane >> 4) << 3;        // 0,8,16,24 (k sub-offset)
    const int qj  = lane & 15;               // q (A row / D col j) index
    const int q4  = (lane >> 4) << 2;        // D row base
    const int rowA = g*12 + qj;              // LDS row for Q/K frags (garbage rows ok)
    const f32x4 zf = {0.f, 0.f, 0.f, 0.f};
    #pragma unroll
    for (int hh = 0; hh < 8; hh++) {
        FragU qa, ka;
        if (ko < 16) {
            int colb = (hh*16 + ko) << 1;
            int adr  = ((rowA << 8) + colb) ^ ((rowA & 7) << 4);
            qa.u = *(const us8*)((const char*)QA + adr);
            ka.u = *(const us8*)((const char*)KB + adr);
        } else {
            qa.u = *(const us8*)((const char*)ZR);
            ka.u = qa.u;
        }
        f32x4 s = __builtin_amdgcn_mfma_f32_16x16x32_bf16(qa.b, ka.b, zf, 0, 0, 0);
        // softmax per D row q=q4+r over the 16 j-lanes
        #pragma unroll
        for (int r = 0; r < 4; r++) {
            float sv = s[r]*0.25f;
            if (qj >= 12 || (MASK && qj > q4 + r)) sv = -1e30f;
            float mx = sv;
            #pragma unroll
            for (int off = 1; off < 16; off <<= 1) mx = fmaxf(mx, __shfl_xor(mx, off));
            float e = __expf(sv - mx);
            float sm = e;
            #pragma unroll
            for (int off = 1; off < 16; off <<= 1) sm += __shfl_xor(sm, off);
            s[r] = e / sm;
        }
        if (qj < 12) {                        // write P rows q4..q4+3, col j=qj (bf16)
            #pragma unroll
            for (int r = 0; r < 4; r++) {
                int q = q4 + r;
                *(u16*)((char*)ps + ((q*64 + (qj << 1)) ^ ((q & 3) << 4))) = f2bf(s[r]);
            }
        }
        // PV: A from ps (row=qj, k=ko+i); B from VB (col d=qj, k rows g*12+ko+i)
        FragU pa, vb;
        pa.u = *(const us8*)((const char*)ps + ((qj*64 + (ko << 1)) ^ ((qj & 3) << 4)));
        #pragma unroll
        for (int i = 0; i < 8; i++) {
            int rv = g*12 + ko + i; rv = rv > 47 ? 47 : rv;     // clamp (A is zero there)
            vb.u[i] = *(const u16*)((const char*)VB +
                      (((rv << 8) + ((hh*16 + qj) << 1)) ^ ((rv & 7) << 4)));
        }
        f32x4 o = __builtin_amdgcn_mfma_f32_16x16x32_bf16(pa.b, vb.b, zf, 0, 0, 0);
        #pragma unroll
        for (int r = 0; r < 4; r++) {
            int q = q4 + r;
            if (q < 12) {
                int row = g*12 + q;
                *(u16*)((char*)QA + (((row << 8) + ((hh*16 + qj) << 1)) ^ ((row & 7) << 4)))
                    = f2bf(o[r]);
            }
        }
    }
}

// in-register LN over MFMA D-layout regs; lnbuf = float[48*4*2]; contains one barrier
__device__ __forceinline__ void ln_inreg(f32x4 (&v)[3][2], float* lnbuf,
                                         const float* __restrict__ g, const float* __restrict__ bb,
                                         int wave, int lane) {
    float gc[2], bc[2];
    #pragma unroll
    for (int nl = 0; nl < 2; nl++) {
        int col = (wave*2 + nl)*16 + (lane & 15);
        gc[nl] = g[col]; bc[nl] = bb[col];
    }
    #pragma unroll
    for (int mt = 0; mt < 3; mt++)
    #pragma unroll
    for (int r = 0; r < 4; r++) {
        float a = v[mt][0][r], c = v[mt][1][r];
        float p = a + c, q = a*a + c*c;
        #pragma unroll
        for (int off = 1; off < 16; off <<= 1) { p += __shfl_xor(p, off); q += __shfl_xor(q, off); }
        if ((lane & 15) == 0) {
            int row = mt*16 + ((lane >> 4) << 2) + r;
            lnbuf[(row*4 + wave)*2]     = p;
            lnbuf[(row*4 + wave)*2 + 1] = q;
        }
    }
    __syncthreads();
    #pragma unroll
    for (int mt = 0; mt < 3; mt++)
    #pragma unroll
    for (int r = 0; r < 4; r++) {
        int row = mt*16 + ((lane >> 4) << 2) + r;
        float sum = 0.f, ss = 0.f;
        #pragma unroll
        for (int w2 = 0; w2 < 4; w2++) { sum += lnbuf[(row*4 + w2)*2]; ss += lnbuf[(row*4 + w2)*2 + 1]; }
        float m   = sum * (1.f/128.f);
        float var = ss * (1.f/128.f) - m*m;
        float inv = rsqrtf(var + EPS_);
        #pragma unroll
        for (int nl = 0; nl < 2; nl++)
            v[mt][nl][r] = (v[mt][nl][r] - m)*inv*gc[nl] + bc[nl];
    }
}

// ---------------- whole decoder layer, fused (4 bn per block, 4 waves) ----------------
template<bool EMB, bool FIN>
__global__ void __launch_bounds__(THREADS)
k_layer(float* __restrict__ h, const float* __restrict__ x,
        const float* __restrict__ ew, const float* __restrict__ ebp, const float* __restrict__ pe,
        const float* __restrict__ encx, const u16* __restrict__ lw,
        const float* __restrict__ sab, const float* __restrict__ ckb, const float* __restrict__ cab,
        const float* __restrict__ fb1, const float* __restrict__ fb2,
        const float* __restrict__ lg, const float* __restrict__ lb,
        const float* __restrict__ fcw, const float* __restrict__ fcb,
        float* __restrict__ outp) {
    __shared__ __align__(16) u16 P0[6144], P1[6144], P2[6144], P3[6144], ZR[128];
    __shared__ __align__(16) float UN[1024];   // union: lnbuf (384 f) / PS (4x512 u16)
    float* lnbuf = UN;
    u16*   PS    = (u16*)UN;

    int t = threadIdx.x, wave = t >> 6, lane = t & 63;
    int bid = blockIdx.x;
    float* hp = h + (size_t)bid * (48*128);

    if (t < 64) ((unsigned*)ZR)[t] = 0;
    if (EMB) stage48_embed(x, ew, ebp, pe, bid*4, P0, t);
    else     stage48(hp, P0, t);
    __syncthreads();                                               // 1

    int gg[3], rr[3];
    #pragma unroll
    for (int mt = 0; mt < 3; mt++) { int m = mt*16 + (lane & 15); gg[mt] = m/12; rr[mt] = m - gg[mt]*12; }

    // ---- SELF: causal conv (residual in regs) ----
    f32x4 cacc[3][2];
    acc_init(cacc, nullptr, wave, lane);
    {
        int sr[3];
        #pragma unroll
        for (int mt = 0; mt < 3; mt++) { int r2 = rr[mt] - 1; sr[mt] = (r2 >= 0) ? gg[mt]*12 + r2 : -1; }
        gemm48_rows(P0, ZR, sr, (const us8*)lw, cacc, wave, lane);
        #pragma unroll
        for (int mt = 0; mt < 3; mt++) sr[mt] = gg[mt]*12 + rr[mt];
        gemm48_rows(P0, ZR, sr, (const us8*)(lw + 16384), cacc, wave, lane);
    }
    acc_store_bf<false>(cacc, P1, wave, lane);                     // conv out
    __syncthreads();                                               // 2

    {   // QKV from conv output
        const us8* sap = (const us8*)(lw + 32768);
        f32x4 a[3][2];
        acc_init(a, sab, wave, lane);        gemm48<4>(P1, sap,        0, a, wave, lane); acc_store_bf<false>(a, P0, wave, lane);
        acc_init(a, sab + 128, wave, lane);  gemm48<4>(P1, sap + 2048, 0, a, wave, lane); acc_store_bf<false>(a, P2, wave, lane);
        acc_init(a, sab + 256, wave, lane);  gemm48<4>(P1, sap + 4096, 0, a, wave, lane); acc_store_bf<false>(a, P3, wave, lane);
    }
    __syncthreads();                                               // 3
    attn_mfma<true>(P0, P2, P3, PS, ZR, wave, lane);
    __syncthreads();                                               // 4

    f32x4 hres[3][2];
    stage48(encx + (size_t)(bid*4) * (S_*E_), P2, t);              // enc0 (P2 free)
    {   // out-proj + residual
        f32x4 a[3][2];
        acc_init(a, sab + 384, wave, lane);
        gemm48<4>(P0, (const us8*)(lw + 81920), 0, a, wave, lane);
        #pragma unroll
        for (int mt = 0; mt < 3; mt++)
        #pragma unroll
        for (int nl = 0; nl < 2; nl++) hres[mt][nl] = a[mt][nl] + cacc[mt][nl];
    }
    ln_inreg(hres, lnbuf, lg, lb, wave, lane);                     // 5 (internal)
    acc_store_bf<false>(hres, P1, wave, lane);                     // h1 (Q input for cross)
    __syncthreads();                                               // 6

    // ---- CROSS (2 encoders, averaged) ----
    f32x4 creg[3][2];
    #pragma unroll
    for (int nl = 0; nl < 2; nl++) {
        int col = (wave*2 + nl)*16 + (lane & 15);
        float bv = cab[3*128 + col] + cab[7*128 + col];
        #pragma unroll
        for (int mt = 0; mt < 3; mt++) { creg[mt][nl][0]=bv; creg[mt][nl][1]=bv; creg[mt][nl][2]=bv; creg[mt][nl][3]=bv; }
    }

    #pragma unroll
    for (int ci = 0; ci < 2; ci++) {
        {   // enc conv -> P3
            f32x4 a[3][2];
            acc_init(a, ckb + ci*128, wave, lane);
            #pragma unroll
            for (int tap = 0; tap < 3; tap++) {
                int sr[3];
                #pragma unroll
                for (int mt = 0; mt < 3; mt++) {
                    int r2 = rr[mt] + tap - 1;
                    sr[mt] = (r2 >= 0 && r2 < 12) ? gg[mt]*12 + r2 : -1;
                }
                gemm48_rows(P2, ZR, sr, (const us8*)(lw + 98304 + (ci*3 + tap)*16384), a, wave, lane);
            }
            acc_store_bf<false>(a, P3, wave, lane);
        }
        __syncthreads();                                           // 7 / 12
        const us8* cap = (const us8*)(lw + 196608 + ci*4*16384);
        f32x4 vr[3][2];
        {
            f32x4 a[3][2];
            acc_init(a, cab + (ci*4 + 0)*128, wave, lane); gemm48<4>(P1, cap,        0, a, wave, lane); acc_store_bf<false>(a, P0, wave, lane);
            acc_init(a, cab + (ci*4 + 1)*128, wave, lane); gemm48<4>(P3, cap + 2048, 0, a, wave, lane); acc_store_bf<false>(a, P2, wave, lane);
            acc_init(vr, cab + (ci*4 + 2)*128, wave, lane); gemm48<4>(P3, cap + 4096, 0, vr, wave, lane);
        }
        __syncthreads();                                           // 8 / 13
        acc_store_bf<false>(vr, P3, wave, lane);
        __syncthreads();                                           // 9 / 14
        attn_mfma<false>(P0, P2, P3, PS, ZR, wave, lane);
        __syncthreads();                                           // 10 / 15
        if (ci == 0) stage48(encx + ((size_t)BN_ + bid*4) * (S_*E_), P2, t);  // enc1 (P2 free)
        gemm48<4>(P0, cap + 6144, 0, creg, wave, lane);            // out-proj accumulate
        if (ci == 0) __syncthreads();                              // 11
    }
    #pragma unroll
    for (int mt = 0; mt < 3; mt++)
    #pragma unroll
    for (int nl = 0; nl < 2; nl++) hres[mt][nl] = hres[mt][nl] + 0.5f*creg[mt][nl];
    __syncthreads();                                               // 16 (guard lnbuf + P1 rewrite)
    ln_inreg(hres, lnbuf, lg + 128, lb + 128, wave, lane);         // 17 (internal)
    acc_store_bf<false>(hres, P1, wave, lane);                     // h2 (FFN input)
    __syncthreads();                                               // 18

    // ---- FFN (chunked mid, ping-pong P2/P3) ----
    f32x4 ffacc[3][2];
    acc_init(ffacc, fb2, wave, lane);
    #pragma unroll
    for (int c = 0; c < 4; c++) {
        u16* MB = (c & 1) ? P3 : P2;
        {
            f32x4 a[3][2];
            acc_init(a, fb1 + c*128, wave, lane);
            gemm48<4>(P1, (const us8*)(lw + 327680) + c*2048, 0, a, wave, lane);
            acc_store_bf<true>(a, MB, wave, lane);
        }
        __syncthreads();                                           // 19..22
        gemm48<16>(MB, (const us8*)(lw + 393216), c*4, ffacc, wave, lane);
    }
    #pragma unroll
    for (int mt = 0; mt < 3; mt++)
    #pragma unroll
    for (int nl = 0; nl < 2; nl++) hres[mt][nl] = hres[mt][nl] + ffacc[mt][nl];
    ln_inreg(hres, lnbuf, lg + 256, lb + 256, wave, lane);         // 23 (internal)

    if (FIN) {
        // fused final projection (OUT=1) with output transpose
        float fw[2];
        #pragma unroll
        for (int nl = 0; nl < 2; nl++) fw[nl] = fcw[(wave*2 + nl)*16 + (lane & 15)];
        float pr[3][4];
        #pragma unroll
        for (int mt = 0; mt < 3; mt++)
        #pragma unroll
        for (int r = 0; r < 4; r++) {
            float p = hres[mt][0][r]*fw[0] + hres[mt][1][r]*fw[1];
            #pragma unroll
            for (int off = 1; off < 16; off <<= 1) p += __shfl_xor(p, off);
            pr[mt][r] = p;
        }
        __syncthreads();                                           // lnbuf readers done
        if ((lane & 15) == 0) {
            #pragma unroll
            for (int mt = 0; mt < 3; mt++)
            #pragma unroll
            for (int r = 0; r < 4; r++) {
                int row = mt*16 + ((lane >> 4) << 2) + r;
                lnbuf[row*4 + wave] = pr[mt][r];
            }
        }
        __syncthreads();
        if (t < 48) {
            float s4 = lnbuf[t*4] + lnbuf[t*4+1] + lnbuf[t*4+2] + lnbuf[t*4+3] + fcb[0];
            int bn = bid*4 + t/12, s = t % 12;
            int b = bn / N_, n = bn - b*N_;
            outp[(b*S_ + s)*N_ + n] = s4;
        }
    } else {
        #pragma unroll
        for (int mt = 0; mt < 3; mt++)
        #pragma unroll
        for (int nl = 0; nl < 2; nl++)
        #pragma unroll
        for (int r = 0; r < 4; r++) {
            int row = mt*16 + ((lane >> 4) << 2) + r;
            int col = (wave*2 + nl)*16 + (lane & 15);
            hp[row*128 + col] = hres[mt][nl][r];
        }
    }
}

extern "C" void kernel_launch(void* const* d_in, const int* in_sizes, int n_in,
                              void* d_out, int out_size, void* d_ws, size_t ws_size,
                              hipStream_t stream) {
    const float* x        = (const float*)d_in[0];
    const float* enc_x    = (const float*)d_in[1];
    const float* emb_w    = (const float*)d_in[3];
    const float* emb_b    = (const float*)d_in[4];
    const float* pe       = (const float*)d_in[5];
    const float* conv_q_w = (const float*)d_in[6];
    const float* conv_k_w = (const float*)d_in[7];
    const float* conv_k_b = (const float*)d_in[8];
    const float* sa_w     = (const float*)d_in[9];
    const float* sa_b     = (const float*)d_in[10];
    const float* ca_w     = (const float*)d_in[11];
    const float* ca_b     = (const float*)d_in[12];
    const float* ff_w1    = (const float*)d_in[13];
    const float* ff_b1    = (const float*)d_in[14];
    const float* ff_w2    = (const float*)d_in[15];
    const float* ff_b2    = (const float*)d_in[16];
    const float* ln_g     = (const float*)d_in[17];
    const float* ln_b     = (const float*)d_in[18];
    const float* fc_w     = (const float*)d_in[19];
    const float* fc_b     = (const float*)d_in[20];

    const size_t HN = (size_t)BN_ * S_ * E_;   // 16,711,680 floats
    float* h  = (float*)d_ws;
    u16* wpk  = (u16*)((float*)d_ws + HN);

    k_wpack<<<896, 256, 0, stream>>>(conv_q_w, sa_w, conv_k_w, ca_w, ff_w1, ff_w2, wpk);

    for (int l = 0; l < L_; l++) {
        const u16* lw = wpk + (size_t)l*458752;
        const float* sab = sa_b + l*512;
        const float* ckb = conv_k_b + l*256;
        const float* cab = ca_b + l*1024;
        const float* fb1 = ff_b1 + l*512;
        const float* fb2 = ff_b2 + l*128;
        const float* lg  = ln_g + l*384;
        const float* lb  = ln_b + l*384;
        if (l == 0)
            k_layer<true, false><<<BN_/4, THREADS, 0, stream>>>(h, x, emb_w, emb_b, pe, enc_x, lw,
                sab, ckb, cab, fb1, fb2, lg, lb, fc_w, fc_b, (float*)d_out);
        else if (l == L_-1)
            k_layer<false, true><<<BN_/4, THREADS, 0, stream>>>(h, x, emb_w, emb_b, pe, enc_x, lw,
                sab, ckb, cab, fb1, fb2, lg, lb, fc_w, fc_b, (float*)d_out);
        else
            k_layer<false, false><<<BN_/4, THREADS, 0, stream>>>(h, x, emb_w, emb_b, pe, enc_x, lw,
                sab, ckb, cab, fb1, fb2, lg, lb, fc_w, fc_b, (float*)d_out);
    }
}

// Round 12
// 1819.061 us; speedup vs baseline: 1.5304x; 1.5304x over previous
//
#include <hip/hip_runtime.h>

// f32 storage; bf16 only as MFMA inputs (f32 accumulate). One fused kernel per layer.
// 512 threads / 8 waves per block; each wave owns one 16-col N-tile (NTW=1).
// __launch_bounds__(512, 2): allocator targets 2x the declared min (observed R4/R6/R7)
// => VGPR cap 128, natural pressure ~100 fits => 4 waves/SIMD, no spills.

#define B_   64
#define S_   12
#define N_   170
#define BN_  (B_*N_)      // 10880
#define E_   128
#define L_   4
#define C_   2
#define H_   8
#define DH_  16
#define FF_  512
#define EPS_ 1e-5f
#define THREADS 512

typedef unsigned short u16;
typedef __attribute__((ext_vector_type(4))) float f32x4;
typedef __attribute__((ext_vector_type(8))) u16   us8;
typedef __attribute__((ext_vector_type(4))) u16   us4;
typedef __attribute__((ext_vector_type(8))) __bf16 bf16x8;
union FragU { us8 u; bf16x8 b; };

__device__ __forceinline__ u16 f2bf(float f) {            // native RNE cvt
    __bf16 h = (__bf16)f;
    return __builtin_bit_cast(u16, h);
}
__device__ __forceinline__ float bf2f(u16 s) {
    return __builtin_bit_cast(float, (unsigned)s << 16);
}

// ---------------- weight pre-pack into MFMA B-fragment order ----------------
// Layer layout (u16): cq 2x16384 @0 | sa 4x16384 @32768 | ck 6x16384 @98304
//                     | ca 8x16384 @196608 | ff1 @327680 | ff2 @393216 ; stride 458752
__global__ void k_wpack(const float* __restrict__ cq, const float* __restrict__ sa,
                        const float* __restrict__ ck, const float* __restrict__ ca,
                        const float* __restrict__ f1, const float* __restrict__ f2,
                        u16* __restrict__ wp) {
    int f  = blockIdx.x * 256 + threadIdx.x;    // frag id, total 229376
    int l  = f / 57344, fl = f % 57344;
    const float* src; int sk, so, KS, q;
    if (fl < 4096)        { int tap = fl >> 11; q = fl & 2047; KS = 4;
                            src = cq + (size_t)l*49152 + tap;            sk = 3;   so = 384; }
    else if (fl < 12288)  { int j = (fl - 4096) >> 11; q = fl & 2047; KS = 4;
                            src = sa + (size_t)(l*4 + j)*16384;          sk = 128; so = 1;   }
    else if (fl < 24576)  { int ct = (fl - 12288) >> 11; q = fl & 2047; KS = 4;
                            int ci = ct / 3, tap = ct % 3;
                            src = ck + (size_t)(l*2 + ci)*49152 + tap;   sk = 3;   so = 384; }
    else if (fl < 40960)  { int cj = (fl - 24576) >> 11; q = fl & 2047; KS = 4;
                            src = ca + (size_t)(l*8 + cj)*16384;         sk = 128; so = 1;   }
    else if (fl < 49152)  { q = fl - 40960; KS = 4;
                            src = f1 + (size_t)l*65536;                  sk = 512; so = 1;   }
    else                  { q = fl - 49152; KS = 16;
                            src = f2 + (size_t)l*65536;                  sk = 128; so = 1;   }
    int lane = q & 63, tt = q >> 6;
    int ks = tt % KS, ntile = tt / KS;
    int k0 = ks*32 + ((lane >> 4) << 3);
    int o  = ntile*16 + (lane & 15);
    us8 w;
    #pragma unroll
    for (int i = 0; i < 8; i++) w[i] = f2bf(src[(size_t)(k0 + i)*sk + (size_t)o*so]);
    *(us8*)(wp + (size_t)f*8) = w;
}

// ---------------- device helpers ----------------
__device__ __forceinline__ void stage48(const float* __restrict__ src, u16* dst, int t) {
    for (int i = t; i < 1536; i += THREADS) {
        const f32x4 v = __builtin_nontemporal_load(((const f32x4*)src) + i);
        int elem = i << 2;
        int row = elem >> 7, colb = (elem & 127) << 1;
        us4 w; w[0] = f2bf(v[0]); w[1] = f2bf(v[1]); w[2] = f2bf(v[2]); w[3] = f2bf(v[3]);
        *(us4*)((char*)dst + (((row << 8) + colb) ^ ((row & 7) << 4))) = w;
    }
}

__device__ __forceinline__ void stage48_embed(const float* __restrict__ x,
    const float* __restrict__ ew, const float* __restrict__ eb,
    const float* __restrict__ pe, int bn0, u16* dst, int t) {
    for (int i = t; i < 1536; i += THREADS) {
        int elem = i << 2;
        int row = elem >> 7, col = elem & 127;
        int g = row / 12, s = row - g*12;
        int bn = bn0 + g, b = bn / N_, n = bn - b*N_;
        float xv = __builtin_nontemporal_load(x + (b*S_ + s)*N_ + n);
        const f32x4 w  = *(const f32x4*)(ew + col);
        const f32x4 bb = *(const f32x4*)(eb + col);
        const f32x4 p  = *(const f32x4*)(pe + s*E_ + col);
        us4 o; o[0] = f2bf(xv*w[0] + bb[0] + p[0]); o[1] = f2bf(xv*w[1] + bb[1] + p[1]);
               o[2] = f2bf(xv*w[2] + bb[2] + p[2]); o[3] = f2bf(xv*w[3] + bb[3] + p[3]);
        *(us4*)((char*)dst + (((row << 8) + (col << 1)) ^ ((row & 7) << 4))) = o;
    }
}

__device__ __forceinline__ void acc_init(f32x4 (&acc)[3], const float* bias, int wave, int lane) {
    float bv = bias ? bias[wave*16 + (lane & 15)] : 0.f;
    #pragma unroll
    for (int mt = 0; mt < 3; mt++) {
        acc[mt][0] = bv; acc[mt][1] = bv; acc[mt][2] = bv; acc[mt][3] = bv;
    }
}

// GEMM: D[48][wave's 16 cols] += A[48][128] * W ; A swizzled bf16 LDS (256B rows)
template<int KSTOT>
__device__ __forceinline__ void gemm48(const u16* A, const us8* __restrict__ WP, int ksOff,
                                       f32x4 (&acc)[3], int wave, int lane) {
    #pragma unroll
    for (int ks = 0; ks < 4; ks++) {
        bf16x8 a[3];
        #pragma unroll
        for (int mt = 0; mt < 3; mt++) {
            int row  = mt*16 + (lane & 15);
            int colb = (ks*32 + ((lane >> 4) << 3)) << 1;
            FragU fu; fu.u = *(const us8*)((const char*)A + (((row << 8) + colb) ^ ((row & 7) << 4)));
            a[mt] = fu.b;
        }
        FragU fb; fb.u = WP[(wave*KSTOT + ksOff + ks)*64 + lane];
        #pragma unroll
        for (int mt = 0; mt < 3; mt++)
            acc[mt] = __builtin_amdgcn_mfma_f32_16x16x32_bf16(a[mt], fb.b, acc[mt], 0, 0, 0);
    }
}

// GEMM with per-mtile shifted source rows (conv taps; sr<0 -> zero row)
__device__ __forceinline__ void gemm48_rows(const u16* A, const u16* ZR, const int (&sr)[3],
                                            const us8* __restrict__ WP,
                                            f32x4 (&acc)[3], int wave, int lane) {
    #pragma unroll
    for (int ks = 0; ks < 4; ks++) {
        bf16x8 a[3];
        #pragma unroll
        for (int mt = 0; mt < 3; mt++) {
            int colb = (ks*32 + ((lane >> 4) << 3)) << 1;
            const char* p = (sr[mt] >= 0)
                ? (const char*)A + (((sr[mt] << 8) + colb) ^ ((sr[mt] & 7) << 4))
                : (const char*)ZR + colb;
            FragU fu; fu.u = *(const us8*)p;
            a[mt] = fu.b;
        }
        FragU fb; fb.u = WP[(wave*4 + ks)*64 + lane];
        #pragma unroll
        for (int mt = 0; mt < 3; mt++)
            acc[mt] = __builtin_amdgcn_mfma_f32_16x16x32_bf16(a[mt], fb.b, acc[mt], 0, 0, 0);
    }
}

template<bool RELU>
__device__ __forceinline__ void acc_store_bf(const f32x4 (&acc)[3], u16* Bp, int wave, int lane) {
    #pragma unroll
    for (int mt = 0; mt < 3; mt++)
    #pragma unroll
    for (int r = 0; r < 4; r++) {
        int row = mt*16 + ((lane >> 4) << 2) + r;
        int col = wave*16 + (lane & 15);
        float v = acc[mt][r];
        if (RELU) v = fmaxf(v, 0.f);
        *(u16*)((char*)Bp + (((row << 8) + (col << 1)) ^ ((row & 7) << 4))) = f2bf(v);
    }
}

__device__ __forceinline__ void ld16(const u16* Bf, int row, int colb, float* o16) {
    int x = (row & 7) << 4;
    int base = (row << 8) + colb;
    us8 u0 = *(const us8*)((const char*)Bf + (base ^ x));
    us8 u1 = *(const us8*)((const char*)Bf + ((base + 16) ^ x));
    #pragma unroll
    for (int d = 0; d < 8; d++) { o16[d] = bf2f(u0[d]); o16[8+d] = bf2f(u1[d]); }
}

// 384 tasks = 4bn x 8heads x 12 qrows; Q tile replaced in place by attention output
template<bool MASK>
__device__ __forceinline__ void attn48(u16* QA, const u16* KB, const u16* VB, int t) {
    if (t < 384) {
        int g = t / 96, rem = t % 96;
        int hh = rem / 12, qi = rem % 12;
        int hb2 = hh << 5;
        int rq = g*12 + qi;
        float qv[16]; ld16(QA, rq, hb2, qv);
        float sc[12]; float mx = -1e30f;
        #pragma unroll
        for (int j = 0; j < 12; j++) {
            float kv[16]; ld16(KB, g*12 + j, hb2, kv);
            float s = 0.f;
            #pragma unroll
            for (int d = 0; d < 16; d++) s += qv[d]*kv[d];
            s *= 0.25f;
            if (MASK && j > qi) s = -1e30f;
            sc[j] = s; mx = fmaxf(mx, s);
        }
        float sum = 0.f;
        #pragma unroll
        for (int j = 0; j < 12; j++) { sc[j] = __expf(sc[j] - mx); sum += sc[j]; }
        float inv = 1.f/sum;
        float ov[16];
        #pragma unroll
        for (int d = 0; d < 16; d++) ov[d] = 0.f;
        #pragma unroll
        for (int j = 0; j < 12; j++) {
            float vv[16]; ld16(VB, g*12 + j, hb2, vv);
            #pragma unroll
            for (int d = 0; d < 16; d++) ov[d] += sc[j]*vv[d];
        }
        int x = (rq & 7) << 4;
        us8 w0, w1;
        #pragma unroll
        for (int d = 0; d < 8; d++) { w0[d] = f2bf(ov[d]*inv); w1[d] = f2bf(ov[8+d]*inv); }
        *(us8*)((char*)QA + (((rq << 8) + hb2) ^ x))      = w0;
        *(us8*)((char*)QA + (((rq << 8) + hb2 + 16) ^ x)) = w1;
    }
}

// in-register LN over MFMA D-layout regs; lnbuf = float[48*8*2]; contains one barrier
__device__ __forceinline__ void ln_inreg(f32x4 (&v)[3], float* lnbuf,
                                         const float* __restrict__ g, const float* __restrict__ bb,
                                         int wave, int lane) {
    int col = wave*16 + (lane & 15);
    float gc = g[col], bc = bb[col];
    #pragma unroll
    for (int mt = 0; mt < 3; mt++)
    #pragma unroll
    for (int r = 0; r < 4; r++) {
        float a = v[mt][r];
        float p = a, q = a*a;
        #pragma unroll
        for (int off = 1; off < 16; off <<= 1) { p += __shfl_xor(p, off); q += __shfl_xor(q, off); }
        if ((lane & 15) == 0) {
            int row = mt*16 + ((lane >> 4) << 2) + r;
            lnbuf[(row*8 + wave)*2]     = p;
            lnbuf[(row*8 + wave)*2 + 1] = q;
        }
    }
    __syncthreads();
    #pragma unroll
    for (int mt = 0; mt < 3; mt++)
    #pragma unroll
    for (int r = 0; r < 4; r++) {
        int row = mt*16 + ((lane >> 4) << 2) + r;
        float sum = 0.f, ss = 0.f;
        #pragma unroll
        for (int w2 = 0; w2 < 8; w2++) { sum += lnbuf[(row*8 + w2)*2]; ss += lnbuf[(row*8 + w2)*2 + 1]; }
        float m   = sum * (1.f/128.f);
        float var = ss * (1.f/128.f) - m*m;
        float inv = rsqrtf(var + EPS_);
        v[mt][r] = (v[mt][r] - m)*inv*gc + bc;
    }
}

// ---------------- whole decoder layer, fused (4 bn per block, 8 waves) ----------------
template<bool EMB, bool FIN>
__global__ void __launch_bounds__(THREADS, 2)
k_layer(float* __restrict__ h, const float* __restrict__ x,
        const float* __restrict__ ew, const float* __restrict__ ebp, const float* __restrict__ pe,
        const float* __restrict__ encx, const u16* __restrict__ lw,
        const float* __restrict__ sab, const float* __restrict__ ckb, const float* __restrict__ cab,
        const float* __restrict__ fb1, const float* __restrict__ fb2,
        const float* __restrict__ lg, const float* __restrict__ lb,
        const float* __restrict__ fcw, const float* __restrict__ fcb,
        float* __restrict__ outp) {
    __shared__ __align__(16) u16 P0[6144], P1[6144], P2[6144], P3[6144], ZR[128];
    __shared__ __align__(16) float lnbuf[48*8*2];

    int t = threadIdx.x, wave = t >> 6, lane = t & 63;
    int bid = blockIdx.x;
    float* hp = h + (size_t)bid * (48*128);

    if (t < 64) ((unsigned*)ZR)[t] = 0;
    if (EMB) stage48_embed(x, ew, ebp, pe, bid*4, P0, t);
    else     stage48(hp, P0, t);
    __syncthreads();                                               // 1

    int gg[3], rr[3];
    #pragma unroll
    for (int mt = 0; mt < 3; mt++) { int m = mt*16 + (lane & 15); gg[mt] = m/12; rr[mt] = m - gg[mt]*12; }

    // ---- SELF: causal conv (residual in regs) ----
    f32x4 cacc[3];
    acc_init(cacc, nullptr, wave, lane);
    {
        int sr[3];
        #pragma unroll
        for (int mt = 0; mt < 3; mt++) { int r2 = rr[mt] - 1; sr[mt] = (r2 >= 0) ? gg[mt]*12 + r2 : -1; }
        gemm48_rows(P0, ZR, sr, (const us8*)lw, cacc, wave, lane);
        #pragma unroll
        for (int mt = 0; mt < 3; mt++) sr[mt] = gg[mt]*12 + rr[mt];
        gemm48_rows(P0, ZR, sr, (const us8*)(lw + 16384), cacc, wave, lane);
    }
    acc_store_bf<false>(cacc, P1, wave, lane);                     // conv out
    __syncthreads();                                               // 2

    {   // QKV from conv output
        const us8* sap = (const us8*)(lw + 32768);
        f32x4 a[3];
        acc_init(a, sab, wave, lane);        gemm48<4>(P1, sap,        0, a, wave, lane); acc_store_bf<false>(a, P0, wave, lane);
        acc_init(a, sab + 128, wave, lane);  gemm48<4>(P1, sap + 2048, 0, a, wave, lane); acc_store_bf<false>(a, P2, wave, lane);
        acc_init(a, sab + 256, wave, lane);  gemm48<4>(P1, sap + 4096, 0, a, wave, lane); acc_store_bf<false>(a, P3, wave, lane);
    }
    __syncthreads();                                               // 3
    attn48<true>(P0, P2, P3, t);
    __syncthreads();                                               // 4

    f32x4 hres[3];
    stage48(encx + (size_t)(bid*4) * (S_*E_), P2, t);              // enc0 (P2 free)
    {   // out-proj + residual
        f32x4 a[3];
        acc_init(a, sab + 384, wave, lane);
        gemm48<4>(P0, (const us8*)(lw + 81920), 0, a, wave, lane);
        #pragma unroll
        for (int mt = 0; mt < 3; mt++) hres[mt] = a[mt] + cacc[mt];
    }
    ln_inreg(hres, lnbuf, lg, lb, wave, lane);                     // 5 (internal)
    acc_store_bf<false>(hres, P1, wave, lane);                     // h1 (Q input for cross)
    __syncthreads();                                               // 6

    // ---- CROSS (2 encoders, averaged) ----
    f32x4 creg[3];
    {
        int col = wave*16 + (lane & 15);
        float bv = cab[3*128 + col] + cab[7*128 + col];
        #pragma unroll
        for (int mt = 0; mt < 3; mt++) { creg[mt][0]=bv; creg[mt][1]=bv; creg[mt][2]=bv; creg[mt][3]=bv; }
    }

    #pragma unroll
    for (int ci = 0; ci < 2; ci++) {
        {   // enc conv -> P3
            f32x4 a[3];
            acc_init(a, ckb + ci*128, wave, lane);
            #pragma unroll
            for (int tap = 0; tap < 3; tap++) {
                int sr[3];
                #pragma unroll
                for (int mt = 0; mt < 3; mt++) {
                    int r2 = rr[mt] + tap - 1;
                    sr[mt] = (r2 >= 0 && r2 < 12) ? gg[mt]*12 + r2 : -1;
                }
                gemm48_rows(P2, ZR, sr, (const us8*)(lw + 98304 + (ci*3 + tap)*16384), a, wave, lane);
            }
            acc_store_bf<false>(a, P3, wave, lane);
        }
        __syncthreads();                                           // 7 / 12
        const us8* cap = (const us8*)(lw + 196608 + ci*4*16384);
        f32x4 vr[3];
        {
            f32x4 a[3];
            acc_init(a, cab + (ci*4 + 0)*128, wave, lane); gemm48<4>(P1, cap,        0, a, wave, lane); acc_store_bf<false>(a, P0, wave, lane);
            acc_init(a, cab + (ci*4 + 1)*128, wave, lane); gemm48<4>(P3, cap + 2048, 0, a, wave, lane); acc_store_bf<false>(a, P2, wave, lane);
            acc_init(vr, cab + (ci*4 + 2)*128, wave, lane); gemm48<4>(P3, cap + 4096, 0, vr, wave, lane);
        }
        __syncthreads();                                           // 8 / 13
        acc_store_bf<false>(vr, P3, wave, lane);
        __syncthreads();                                           // 9 / 14
        attn48<false>(P0, P2, P3, t);
        __syncthreads();                                           // 10 / 15
        if (ci == 0) stage48(encx + ((size_t)BN_ + bid*4) * (S_*E_), P2, t);  // enc1 (P2 free)
        gemm48<4>(P0, cap + 6144, 0, creg, wave, lane);            // out-proj accumulate
        if (ci == 0) __syncthreads();                              // 11
    }
    #pragma unroll
    for (int mt = 0; mt < 3; mt++) hres[mt] = hres[mt] + 0.5f*creg[mt];
    __syncthreads();                                               // 16 (guard lnbuf + P1 rewrite)
    ln_inreg(hres, lnbuf, lg + 128, lb + 128, wave, lane);         // 17 (internal)
    acc_store_bf<false>(hres, P1, wave, lane);                     // h2 (FFN input)
    __syncthreads();                                               // 18

    // ---- FFN (chunked mid, ping-pong P2/P3) ----
    f32x4 ffacc[3];
    acc_init(ffacc, fb2, wave, lane);
    #pragma unroll
    for (int c = 0; c < 4; c++) {
        u16* MB = (c & 1) ? P3 : P2;
        {
            f32x4 a[3];
            acc_init(a, fb1 + c*128, wave, lane);
            gemm48<4>(P1, (const us8*)(lw + 327680) + c*2048, 0, a, wave, lane);
            acc_store_bf<true>(a, MB, wave, lane);
        }
        __syncthreads();                                           // 19..22
        gemm48<16>(MB, (const us8*)(lw + 393216), c*4, ffacc, wave, lane);
    }
    #pragma unroll
    for (int mt = 0; mt < 3; mt++) hres[mt] = hres[mt] + ffacc[mt];
    ln_inreg(hres, lnbuf, lg + 256, lb + 256, wave, lane);         // 23 (internal)

    if (FIN) {
        // fused final projection (OUT=1) with output transpose
        float fw = fcw[wave*16 + (lane & 15)];
        float pr[3][4];
        #pragma unroll
        for (int mt = 0; mt < 3; mt++)
        #pragma unroll
        for (int r = 0; r < 4; r++) {
            float p = hres[mt][r]*fw;
            #pragma unroll
            for (int off = 1; off < 16; off <<= 1) p += __shfl_xor(p, off);
            pr[mt][r] = p;
        }
        __syncthreads();                                           // lnbuf readers done
        if ((lane & 15) == 0) {
            #pragma unroll
            for (int mt = 0; mt < 3; mt++)
            #pragma unroll
            for (int r = 0; r < 4; r++) {
                int row = mt*16 + ((lane >> 4) << 2) + r;
                lnbuf[row*8 + wave] = pr[mt][r];
            }
        }
        __syncthreads();
        if (t < 48) {
            float s8 = fcb[0];
            #pragma unroll
            for (int w2 = 0; w2 < 8; w2++) s8 += lnbuf[t*8 + w2];
            int bn = bid*4 + t/12, s = t % 12;
            int b = bn / N_, n = bn - b*N_;
            outp[(b*S_ + s)*N_ + n] = s8;
        }
    } else {
        #pragma unroll
        for (int mt = 0; mt < 3; mt++)
        #pragma unroll
        for (int r = 0; r < 4; r++) {
            int row = mt*16 + ((lane >> 4) << 2) + r;
            int col = wave*16 + (lane & 15);
            hp[row*128 + col] = hres[mt][r];
        }
    }
}

extern "C" void kernel_launch(void* const* d_in, const int* in_sizes, int n_in,
                              void* d_out, int out_size, void* d_ws, size_t ws_size,
                              hipStream_t stream) {
    const float* x        = (const float*)d_in[0];
    const float* enc_x    = (const float*)d_in[1];
    const float* emb_w    = (const float*)d_in[3];
    const float* emb_b    = (const float*)d_in[4];
    const float* pe       = (const float*)d_in[5];
    const float* conv_q_w = (const float*)d_in[6];
    const float* conv_k_w = (const float*)d_in[7];
    const float* conv_k_b = (const float*)d_in[8];
    const float* sa_w     = (const float*)d_in[9];
    const float* sa_b     = (const float*)d_in[10];
    const float* ca_w     = (const float*)d_in[11];
    const float* ca_b     = (const float*)d_in[12];
    const float* ff_w1    = (const float*)d_in[13];
    const float* ff_b1    = (const float*)d_in[14];
    const float* ff_w2    = (const float*)d_in[15];
    const float* ff_b2    = (const float*)d_in[16];
    const float* ln_g     = (const float*)d_in[17];
    const float* ln_b     = (const float*)d_in[18];
    const float* fc_w     = (const float*)d_in[19];
    const float* fc_b     = (const float*)d_in[20];

    const size_t HN = (size_t)BN_ * S_ * E_;
    float* h  = (float*)d_ws;
    u16* wpk  = (u16*)((float*)d_ws + HN);

    k_wpack<<<896, 256, 0, stream>>>(conv_q_w, sa_w, conv_k_w, ca_w, ff_w1, ff_w2, wpk);

    for (int l = 0; l < L_; l++) {
        const u16* lw = wpk + (size_t)l*458752;
        const float* sab = sa_b + l*512;
        const float* ckb = conv_k_b + l*256;
        const float* cab = ca_b + l*1024;
        const float* fb1 = ff_b1 + l*512;
        const float* fb2 = ff_b2 + l*128;
        const float* lg  = ln_g + l*384;
        const float* lb  = ln_b + l*384;
        if (l == 0)
            k_layer<true, false><<<BN_/4, THREADS, 0, stream>>>(h, x, emb_w, emb_b, pe, enc_x, lw,
                sab, ckb, cab, fb1, fb2, lg, lb, fc_w, fc_b, (float*)d_out);
        else if (l == L_-1)
            k_layer<false, true><<<BN_/4, THREADS, 0, stream>>>(h, x, emb_w, emb_b, pe, enc_x, lw,
                sab, ckb, cab, fb1, fb2, lg, lb, fc_w, fc_b, (float*)d_out);
        else
            k_layer<false, false><<<BN_/4, THREADS, 0, stream>>>(h, x, emb_w, emb_b, pe, enc_x, lw,
                sab, ckb, cab, fb1, fb2, lg, lb, fc_w, fc_b, (float*)d_out);
    }
}

// Round 13
// 1808.807 us; speedup vs baseline: 1.5391x; 1.0057x over previous
//
#include <hip/hip_runtime.h>

// f32 storage; bf16 only as MFMA inputs (f32 accumulate). One fused kernel per layer.
// 512 threads / 8 waves per block; each wave owns one 16-col N-tile (NTW=1).
// __launch_bounds__(512, 2): allocator targets 2x declared min => VGPR cap 128 (R12-proven).
// R13: no nontemporal hints (h/enc_x are re-read across layers -> keep them L2/L3-hot);
//      P4 tile so cross-attn V is written directly (2 fewer barriers/layer).

#define B_   64
#define S_   12
#define N_   170
#define BN_  (B_*N_)      // 10880
#define E_   128
#define L_   4
#define C_   2
#define H_   8
#define DH_  16
#define FF_  512
#define EPS_ 1e-5f
#define THREADS 512

typedef unsigned short u16;
typedef __attribute__((ext_vector_type(4))) float f32x4;
typedef __attribute__((ext_vector_type(8))) u16   us8;
typedef __attribute__((ext_vector_type(4))) u16   us4;
typedef __attribute__((ext_vector_type(8))) __bf16 bf16x8;
union FragU { us8 u; bf16x8 b; };

__device__ __forceinline__ u16 f2bf(float f) {            // native RNE cvt
    __bf16 h = (__bf16)f;
    return __builtin_bit_cast(u16, h);
}
__device__ __forceinline__ float bf2f(u16 s) {
    return __builtin_bit_cast(float, (unsigned)s << 16);
}

// ---------------- weight pre-pack into MFMA B-fragment order ----------------
// Layer layout (u16): cq 2x16384 @0 | sa 4x16384 @32768 | ck 6x16384 @98304
//                     | ca 8x16384 @196608 | ff1 @327680 | ff2 @393216 ; stride 458752
__global__ void k_wpack(const float* __restrict__ cq, const float* __restrict__ sa,
                        const float* __restrict__ ck, const float* __restrict__ ca,
                        const float* __restrict__ f1, const float* __restrict__ f2,
                        u16* __restrict__ wp) {
    int f  = blockIdx.x * 256 + threadIdx.x;    // frag id, total 229376
    int l  = f / 57344, fl = f % 57344;
    const float* src; int sk, so, KS, q;
    if (fl < 4096)        { int tap = fl >> 11; q = fl & 2047; KS = 4;
                            src = cq + (size_t)l*49152 + tap;            sk = 3;   so = 384; }
    else if (fl < 12288)  { int j = (fl - 4096) >> 11; q = fl & 2047; KS = 4;
                            src = sa + (size_t)(l*4 + j)*16384;          sk = 128; so = 1;   }
    else if (fl < 24576)  { int ct = (fl - 12288) >> 11; q = fl & 2047; KS = 4;
                            int ci = ct / 3, tap = ct % 3;
                            src = ck + (size_t)(l*2 + ci)*49152 + tap;   sk = 3;   so = 384; }
    else if (fl < 40960)  { int cj = (fl - 24576) >> 11; q = fl & 2047; KS = 4;
                            src = ca + (size_t)(l*8 + cj)*16384;         sk = 128; so = 1;   }
    else if (fl < 49152)  { q = fl - 40960; KS = 4;
                            src = f1 + (size_t)l*65536;                  sk = 512; so = 1;   }
    else                  { q = fl - 49152; KS = 16;
                            src = f2 + (size_t)l*65536;                  sk = 128; so = 1;   }
    int lane = q & 63, tt = q >> 6;
    int ks = tt % KS, ntile = tt / KS;
    int k0 = ks*32 + ((lane >> 4) << 3);
    int o  = ntile*16 + (lane & 15);
    us8 w;
    #pragma unroll
    for (int i = 0; i < 8; i++) w[i] = f2bf(src[(size_t)(k0 + i)*sk + (size_t)o*so]);
    *(us8*)(wp + (size_t)f*8) = w;
}

// ---------------- device helpers ----------------
__device__ __forceinline__ void stage48(const float* __restrict__ src, u16* dst, int t) {
    for (int i = t; i < 1536; i += THREADS) {
        const f32x4 v = ((const f32x4*)src)[i];
        int elem = i << 2;
        int row = elem >> 7, colb = (elem & 127) << 1;
        us4 w; w[0] = f2bf(v[0]); w[1] = f2bf(v[1]); w[2] = f2bf(v[2]); w[3] = f2bf(v[3]);
        *(us4*)((char*)dst + (((row << 8) + colb) ^ ((row & 7) << 4))) = w;
    }
}

__device__ __forceinline__ void stage48_embed(const float* __restrict__ x,
    const float* __restrict__ ew, const float* __restrict__ eb,
    const float* __restrict__ pe, int bn0, u16* dst, int t) {
    for (int i = t; i < 1536; i += THREADS) {
        int elem = i << 2;
        int row = elem >> 7, col = elem & 127;
        int g = row / 12, s = row - g*12;
        int bn = bn0 + g, b = bn / N_, n = bn - b*N_;
        float xv = x[(b*S_ + s)*N_ + n];
        const f32x4 w  = *(const f32x4*)(ew + col);
        const f32x4 bb = *(const f32x4*)(eb + col);
        const f32x4 p  = *(const f32x4*)(pe + s*E_ + col);
        us4 o; o[0] = f2bf(xv*w[0] + bb[0] + p[0]); o[1] = f2bf(xv*w[1] + bb[1] + p[1]);
               o[2] = f2bf(xv*w[2] + bb[2] + p[2]); o[3] = f2bf(xv*w[3] + bb[3] + p[3]);
        *(us4*)((char*)dst + (((row << 8) + (col << 1)) ^ ((row & 7) << 4))) = o;
    }
}

__device__ __forceinline__ void acc_init(f32x4 (&acc)[3], const float* bias, int wave, int lane) {
    float bv = bias ? bias[wave*16 + (lane & 15)] : 0.f;
    #pragma unroll
    for (int mt = 0; mt < 3; mt++) {
        acc[mt][0] = bv; acc[mt][1] = bv; acc[mt][2] = bv; acc[mt][3] = bv;
    }
}

// GEMM: D[48][wave's 16 cols] += A[48][128] * W ; A swizzled bf16 LDS (256B rows)
template<int KSTOT>
__device__ __forceinline__ void gemm48(const u16* A, const us8* __restrict__ WP, int ksOff,
                                       f32x4 (&acc)[3], int wave, int lane) {
    #pragma unroll
    for (int ks = 0; ks < 4; ks++) {
        bf16x8 a[3];
        #pragma unroll
        for (int mt = 0; mt < 3; mt++) {
            int row  = mt*16 + (lane & 15);
            int colb = (ks*32 + ((lane >> 4) << 3)) << 1;
            FragU fu; fu.u = *(const us8*)((const char*)A + (((row << 8) + colb) ^ ((row & 7) << 4)));
            a[mt] = fu.b;
        }
        FragU fb; fb.u = WP[(wave*KSTOT + ksOff + ks)*64 + lane];
        #pragma unroll
        for (int mt = 0; mt < 3; mt++)
            acc[mt] = __builtin_amdgcn_mfma_f32_16x16x32_bf16(a[mt], fb.b, acc[mt], 0, 0, 0);
    }
}

// GEMM with per-mtile shifted source rows (conv taps; sr<0 -> zero row)
__device__ __forceinline__ void gemm48_rows(const u16* A, const u16* ZR, const int (&sr)[3],
                                            const us8* __restrict__ WP,
                                            f32x4 (&acc)[3], int wave, int lane) {
    #pragma unroll
    for (int ks = 0; ks < 4; ks++) {
        bf16x8 a[3];
        #pragma unroll
        for (int mt = 0; mt < 3; mt++) {
            int colb = (ks*32 + ((lane >> 4) << 3)) << 1;
            const char* p = (sr[mt] >= 0)
                ? (const char*)A + (((sr[mt] << 8) + colb) ^ ((sr[mt] & 7) << 4))
                : (const char*)ZR + colb;
            FragU fu; fu.u = *(const us8*)p;
            a[mt] = fu.b;
        }
        FragU fb; fb.u = WP[(wave*4 + ks)*64 + lane];
        #pragma unroll
        for (int mt = 0; mt < 3; mt++)
            acc[mt] = __builtin_amdgcn_mfma_f32_16x16x32_bf16(a[mt], fb.b, acc[mt], 0, 0, 0);
    }
}

template<bool RELU>
__device__ __forceinline__ void acc_store_bf(const f32x4 (&acc)[3], u16* Bp, int wave, int lane) {
    #pragma unroll
    for (int mt = 0; mt < 3; mt++)
    #pragma unroll
    for (int r = 0; r < 4; r++) {
        int row = mt*16 + ((lane >> 4) << 2) + r;
        int col = wave*16 + (lane & 15);
        float v = acc[mt][r];
        if (RELU) v = fmaxf(v, 0.f);
        *(u16*)((char*)Bp + (((row << 8) + (col << 1)) ^ ((row & 7) << 4))) = f2bf(v);
    }
}

__device__ __forceinline__ void ld16(const u16* Bf, int row, int colb, float* o16) {
    int x = (row & 7) << 4;
    int base = (row << 8) + colb;
    us8 u0 = *(const us8*)((const char*)Bf + (base ^ x));
    us8 u1 = *(const us8*)((const char*)Bf + ((base + 16) ^ x));
    #pragma unroll
    for (int d = 0; d < 8; d++) { o16[d] = bf2f(u0[d]); o16[8+d] = bf2f(u1[d]); }
}

// 384 tasks = 4bn x 8heads x 12 qrows; Q tile replaced in place by attention output
template<bool MASK>
__device__ __forceinline__ void attn48(u16* QA, const u16* KB, const u16* VB, int t) {
    if (t < 384) {
        int g = t / 96, rem = t % 96;
        int hh = rem / 12, qi = rem % 12;
        int hb2 = hh << 5;
        int rq = g*12 + qi;
        float qv[16]; ld16(QA, rq, hb2, qv);
        float sc[12]; float mx = -1e30f;
        #pragma unroll
        for (int j = 0; j < 12; j++) {
            float kv[16]; ld16(KB, g*12 + j, hb2, kv);
            float s = 0.f;
            #pragma unroll
            for (int d = 0; d < 16; d++) s += qv[d]*kv[d];
            s *= 0.25f;
            if (MASK && j > qi) s = -1e30f;
            sc[j] = s; mx = fmaxf(mx, s);
        }
        float sum = 0.f;
        #pragma unroll
        for (int j = 0; j < 12; j++) { sc[j] = __expf(sc[j] - mx); sum += sc[j]; }
        float inv = 1.f/sum;
        float ov[16];
        #pragma unroll
        for (int d = 0; d < 16; d++) ov[d] = 0.f;
        #pragma unroll
        for (int j = 0; j < 12; j++) {
            float vv[16]; ld16(VB, g*12 + j, hb2, vv);
            #pragma unroll
            for (int d = 0; d < 16; d++) ov[d] += sc[j]*vv[d];
        }
        int x = (rq & 7) << 4;
        us8 w0, w1;
        #pragma unroll
        for (int d = 0; d < 8; d++) { w0[d] = f2bf(ov[d]*inv); w1[d] = f2bf(ov[8+d]*inv); }
        *(us8*)((char*)QA + (((rq << 8) + hb2) ^ x))      = w0;
        *(us8*)((char*)QA + (((rq << 8) + hb2 + 16) ^ x)) = w1;
    }
}

// in-register LN over MFMA D-layout regs; lnbuf = float[48*8*2]; contains one barrier
__device__ __forceinline__ void ln_inreg(f32x4 (&v)[3], float* lnbuf,
                                         const float* __restrict__ g, const float* __restrict__ bb,
                                         int wave, int lane) {
    int col = wave*16 + (lane & 15);
    float gc = g[col], bc = bb[col];
    #pragma unroll
    for (int mt = 0; mt < 3; mt++)
    #pragma unroll
    for (int r = 0; r < 4; r++) {
        float a = v[mt][r];
        float p = a, q = a*a;
        #pragma unroll
        for (int off = 1; off < 16; off <<= 1) { p += __shfl_xor(p, off); q += __shfl_xor(q, off); }
        if ((lane & 15) == 0) {
            int row = mt*16 + ((lane >> 4) << 2) + r;
            lnbuf[(row*8 + wave)*2]     = p;
            lnbuf[(row*8 + wave)*2 + 1] = q;
        }
    }
    __syncthreads();
    #pragma unroll
    for (int mt = 0; mt < 3; mt++)
    #pragma unroll
    for (int r = 0; r < 4; r++) {
        int row = mt*16 + ((lane >> 4) << 2) + r;
        float sum = 0.f, ss = 0.f;
        #pragma unroll
        for (int w2 = 0; w2 < 8; w2++) { sum += lnbuf[(row*8 + w2)*2]; ss += lnbuf[(row*8 + w2)*2 + 1]; }
        float m   = sum * (1.f/128.f);
        float var = ss * (1.f/128.f) - m*m;
        float inv = rsqrtf(var + EPS_);
        v[mt][r] = (v[mt][r] - m)*inv*gc + bc;
    }
}

// ---------------- whole decoder layer, fused (4 bn per block, 8 waves) ----------------
template<bool EMB, bool FIN>
__global__ void __launch_bounds__(THREADS, 2)
k_layer(float* __restrict__ h, const float* __restrict__ x,
        const float* __restrict__ ew, const float* __restrict__ ebp, const float* __restrict__ pe,
        const float* __restrict__ encx, const u16* __restrict__ lw,
        const float* __restrict__ sab, const float* __restrict__ ckb, const float* __restrict__ cab,
        const float* __restrict__ fb1, const float* __restrict__ fb2,
        const float* __restrict__ lg, const float* __restrict__ lb,
        const float* __restrict__ fcw, const float* __restrict__ fcb,
        float* __restrict__ outp) {
    __shared__ __align__(16) u16 P0[6144], P1[6144], P2[6144], P3[6144], P4[6144], ZR[128];
    __shared__ __align__(16) float lnbuf[48*8*2];

    int t = threadIdx.x, wave = t >> 6, lane = t & 63;
    int bid = blockIdx.x;
    float* hp = h + (size_t)bid * (48*128);

    if (t < 64) ((unsigned*)ZR)[t] = 0;
    if (EMB) stage48_embed(x, ew, ebp, pe, bid*4, P0, t);
    else     stage48(hp, P0, t);
    __syncthreads();                                               // 1

    int gg[3], rr[3];
    #pragma unroll
    for (int mt = 0; mt < 3; mt++) { int m = mt*16 + (lane & 15); gg[mt] = m/12; rr[mt] = m - gg[mt]*12; }

    // ---- SELF: causal conv (residual in regs) ----
    f32x4 cacc[3];
    acc_init(cacc, nullptr, wave, lane);
    {
        int sr[3];
        #pragma unroll
        for (int mt = 0; mt < 3; mt++) { int r2 = rr[mt] - 1; sr[mt] = (r2 >= 0) ? gg[mt]*12 + r2 : -1; }
        gemm48_rows(P0, ZR, sr, (const us8*)lw, cacc, wave, lane);
        #pragma unroll
        for (int mt = 0; mt < 3; mt++) sr[mt] = gg[mt]*12 + rr[mt];
        gemm48_rows(P0, ZR, sr, (const us8*)(lw + 16384), cacc, wave, lane);
    }
    acc_store_bf<false>(cacc, P1, wave, lane);                     // conv out
    __syncthreads();                                               // 2

    {   // QKV from conv output
        const us8* sap = (const us8*)(lw + 32768);
        f32x4 a[3];
        acc_init(a, sab, wave, lane);        gemm48<4>(P1, sap,        0, a, wave, lane); acc_store_bf<false>(a, P0, wave, lane);
        acc_init(a, sab + 128, wave, lane);  gemm48<4>(P1, sap + 2048, 0, a, wave, lane); acc_store_bf<false>(a, P2, wave, lane);
        acc_init(a, sab + 256, wave, lane);  gemm48<4>(P1, sap + 4096, 0, a, wave, lane); acc_store_bf<false>(a, P3, wave, lane);
    }
    __syncthreads();                                               // 3
    attn48<true>(P0, P2, P3, t);
    __syncthreads();                                               // 4

    f32x4 hres[3];
    stage48(encx + (size_t)(bid*4) * (S_*E_), P2, t);              // enc0 (P2 free)
    {   // out-proj + residual
        f32x4 a[3];
        acc_init(a, sab + 384, wave, lane);
        gemm48<4>(P0, (const us8*)(lw + 81920), 0, a, wave, lane);
        #pragma unroll
        for (int mt = 0; mt < 3; mt++) hres[mt] = a[mt] + cacc[mt];
    }
    ln_inreg(hres, lnbuf, lg, lb, wave, lane);                     // 5 (internal)
    acc_store_bf<false>(hres, P1, wave, lane);                     // h1 (Q input for cross)
    __syncthreads();                                               // 6

    // ---- CROSS (2 encoders, averaged) ----
    f32x4 creg[3];
    {
        int col = wave*16 + (lane & 15);
        float bv = cab[3*128 + col] + cab[7*128 + col];
        #pragma unroll
        for (int mt = 0; mt < 3; mt++) { creg[mt][0]=bv; creg[mt][1]=bv; creg[mt][2]=bv; creg[mt][3]=bv; }
    }

    #pragma unroll
    for (int ci = 0; ci < 2; ci++) {
        {   // enc conv -> P3 (reads P2 = enc_ci)
            f32x4 a[3];
            acc_init(a, ckb + ci*128, wave, lane);
            #pragma unroll
            for (int tap = 0; tap < 3; tap++) {
                int sr[3];
                #pragma unroll
                for (int mt = 0; mt < 3; mt++) {
                    int r2 = rr[mt] + tap - 1;
                    sr[mt] = (r2 >= 0 && r2 < 12) ? gg[mt]*12 + r2 : -1;
                }
                gemm48_rows(P2, ZR, sr, (const us8*)(lw + 98304 + (ci*3 + tap)*16384), a, wave, lane);
            }
            acc_store_bf<false>(a, P3, wave, lane);
        }
        __syncthreads();                                           // 7 / 10
        const us8* cap = (const us8*)(lw + 196608 + ci*4*16384);
        {   // Q -> P0 (reads P1), K -> P2 (reads P3), V -> P4 (reads P3)
            f32x4 a[3];
            acc_init(a, cab + (ci*4 + 0)*128, wave, lane); gemm48<4>(P1, cap,        0, a, wave, lane); acc_store_bf<false>(a, P0, wave, lane);
            acc_init(a, cab + (ci*4 + 1)*128, wave, lane); gemm48<4>(P3, cap + 2048, 0, a, wave, lane); acc_store_bf<false>(a, P2, wave, lane);
            acc_init(a, cab + (ci*4 + 2)*128, wave, lane); gemm48<4>(P3, cap + 4096, 0, a, wave, lane); acc_store_bf<false>(a, P4, wave, lane);
        }
        __syncthreads();                                           // 8 / 11
        attn48<false>(P0, P2, P4, t);
        __syncthreads();                                           // 9 / 12
        if (ci == 0) stage48(encx + ((size_t)BN_ + bid*4) * (S_*E_), P2, t);  // enc1 (P2 free)
        gemm48<4>(P0, cap + 6144, 0, creg, wave, lane);            // out-proj accumulate
        if (ci == 0) __syncthreads();                              // 9b
    }
    #pragma unroll
    for (int mt = 0; mt < 3; mt++) hres[mt] = hres[mt] + 0.5f*creg[mt];
    __syncthreads();                                               // 13 (guard lnbuf + P1 rewrite)
    ln_inreg(hres, lnbuf, lg + 128, lb + 128, wave, lane);         // 14 (internal)
    acc_store_bf<false>(hres, P1, wave, lane);                     // h2 (FFN input)
    __syncthreads();                                               // 15

    // ---- FFN (chunked mid, ping-pong P2/P3) ----
    f32x4 ffacc[3];
    acc_init(ffacc, fb2, wave, lane);
    #pragma unroll
    for (int c = 0; c < 4; c++) {
        u16* MB = (c & 1) ? P3 : P2;
        {
            f32x4 a[3];
            acc_init(a, fb1 + c*128, wave, lane);
            gemm48<4>(P1, (const us8*)(lw + 327680) + c*2048, 0, a, wave, lane);
            acc_store_bf<true>(a, MB, wave, lane);
        }
        __syncthreads();                                           // 16..19
        gemm48<16>(MB, (const us8*)(lw + 393216), c*4, ffacc, wave, lane);
    }
    #pragma unroll
    for (int mt = 0; mt < 3; mt++) hres[mt] = hres[mt] + ffacc[mt];
    ln_inreg(hres, lnbuf, lg + 256, lb + 256, wave, lane);         // 20 (internal)

    if (FIN) {
        // fused final projection (OUT=1) with output transpose
        float fw = fcw[wave*16 + (lane & 15)];
        float pr[3][4];
        #pragma unroll
        for (int mt = 0; mt < 3; mt++)
        #pragma unroll
        for (int r = 0; r < 4; r++) {
            float p = hres[mt][r]*fw;
            #pragma unroll
            for (int off = 1; off < 16; off <<= 1) p += __shfl_xor(p, off);
            pr[mt][r] = p;
        }
        __syncthreads();                                           // lnbuf readers done
        if ((lane & 15) == 0) {
            #pragma unroll
            for (int mt = 0; mt < 3; mt++)
            #pragma unroll
            for (int r = 0; r < 4; r++) {
                int row = mt*16 + ((lane >> 4) << 2) + r;
                lnbuf[row*8 + wave] = pr[mt][r];
            }
        }
        __syncthreads();
        if (t < 48) {
            float s8 = fcb[0];
            #pragma unroll
            for (int w2 = 0; w2 < 8; w2++) s8 += lnbuf[t*8 + w2];
            int bn = bid*4 + t/12, s = t % 12;
            int b = bn / N_, n = bn - b*N_;
            outp[(b*S_ + s)*N_ + n] = s8;
        }
    } else {
        #pragma unroll
        for (int mt = 0; mt < 3; mt++)
        #pragma unroll
        for (int r = 0; r < 4; r++) {
            int row = mt*16 + ((lane >> 4) << 2) + r;
            int col = wave*16 + (lane & 15);
            hp[row*128 + col] = hres[mt][r];
        }
    }
}

extern "C" void kernel_launch(void* const* d_in, const int* in_sizes, int n_in,
                              void* d_out, int out_size, void* d_ws, size_t ws_size,
                              hipStream_t stream) {
    const float* x        = (const float*)d_in[0];
    const float* enc_x    = (const float*)d_in[1];
    const float* emb_w    = (const float*)d_in[3];
    const float* emb_b    = (const float*)d_in[4];
    const float* pe       = (const float*)d_in[5];
    const float* conv_q_w = (const float*)d_in[6];
    const float* conv_k_w = (const float*)d_in[7];
    const float* conv_k_b = (const float*)d_in[8];
    const float* sa_w     = (const float*)d_in[9];
    const float* sa_b     = (const float*)d_in[10];
    const float* ca_w     = (const float*)d_in[11];
    const float* ca_b     = (const float*)d_in[12];
    const float* ff_w1    = (const float*)d_in[13];
    const float* ff_b1    = (const float*)d_in[14];
    const float* ff_w2    = (const float*)d_in[15];
    const float* ff_b2    = (const float*)d_in[16];
    const float* ln_g     = (const float*)d_in[17];
    const float* ln_b     = (const float*)d_in[18];
    const float* fc_w     = (const float*)d_in[19];
    const float* fc_b     = (const float*)d_in[20];

    const size_t HN = (size_t)BN_ * S_ * E_;
    float* h  = (float*)d_ws;
    u16* wpk  = (u16*)((float*)d_ws + HN);

    k_wpack<<<896, 256, 0, stream>>>(conv_q_w, sa_w, conv_k_w, ca_w, ff_w1, ff_w2, wpk);

    for (int l = 0; l < L_; l++) {
        const u16* lw = wpk + (size_t)l*458752;
        const float* sab = sa_b + l*512;
        const float* ckb = conv_k_b + l*256;
        const float* cab = ca_b + l*1024;
        const float* fb1 = ff_b1 + l*512;
        const float* fb2 = ff_b2 + l*128;
        const float* lg  = ln_g + l*384;
        const float* lb  = ln_b + l*384;
        if (l == 0)
            k_layer<true, false><<<BN_/4, THREADS, 0, stream>>>(h, x, emb_w, emb_b, pe, enc_x, lw,
                sab, ckb, cab, fb1, fb2, lg, lb, fc_w, fc_b, (float*)d_out);
        else if (l == L_-1)
            k_layer<false, true><<<BN_/4, THREADS, 0, stream>>>(h, x, emb_w, emb_b, pe, enc_x, lw,
                sab, ckb, cab, fb1, fb2, lg, lb, fc_w, fc_b, (float*)d_out);
        else
            k_layer<false, false><<<BN_/4, THREADS, 0, stream>>>(h, x, emb_w, emb_b, pe, enc_x, lw,
                sab, ckb, cab, fb1, fb2, lg, lb, fc_w, fc_b, (float*)d_out);
    }
}